// Round 12
// baseline (107.314 us; speedup 1.0000x reference)
//
#include <hip/hip_runtime.h>

typedef unsigned short ushort_t;
typedef unsigned int uint_t;
typedef _Float16 f16;
typedef __attribute__((ext_vector_type(8))) _Float16 f16x8;
typedef __attribute__((ext_vector_type(2))) _Float16 f16x2;
typedef __attribute__((ext_vector_type(4))) float f32x4;

#define B_ 4
#define C_ 256
#define I_ 128
#define N_ 4096
#define KVB 32
#define TOT_IT (N_ / KVB)     // 128
#define LOG2E 1.44269504f

// ws layout in 2-byte units
#define W_F  0ull             // f16 weights: wg@0 wt@32768 wp@65536 wW@98304 (131072)
#define TH_F 131072ull        // f16 theta (pre-scaled by log2e) [B][N][I] (2M)
#define PH_F 2228224ull       // f16 phi [B][N][I] (2M)
#define G3_F 4325376ull       // f16 g, PV-tile layout [B][N/32][4][I][8], lg-XOR swz
#define YP_F 6422528ull       // f16 partials [S][B][N][I] (2,097,152 each)
// lse (f32, base-2) at byte offset 2*(YP_F + S*2097152)

__device__ __forceinline__ float exp2_hw(float x) { return __builtin_amdgcn_exp2f(x); }
__device__ __forceinline__ float log2_hw(float x) { return __builtin_amdgcn_logf(x); }

__device__ __forceinline__ f16x2 pkrtz(float a, float b) {
    auto r = __builtin_amdgcn_cvt_pkrtz(a, b);
    f16x2 o;
    __builtin_memcpy(&o, &r, sizeof(o));
    return o;
}
__device__ __forceinline__ f32x4 mfma16h(f16x8 a, f16x8 b, f32x4 c) {
    return __builtin_amdgcn_mfma_f32_16x16x32_f16(a, b, c, 0, 0, 0);
}
__device__ __forceinline__ f32x4 zero4() { f32x4 z = {0.f, 0.f, 0.f, 0.f}; return z; }
__device__ __forceinline__ void gload_lds16(const void* g, void* lds) {
    __builtin_amdgcn_global_load_lds(
        (const __attribute__((address_space(1))) void*)g,
        (__attribute__((address_space(3))) void*)lds, 16, 0, 0);
}

// ---------------- kernel 1: convert weights to f16 ---------------------------
__global__ __launch_bounds__(256) void k_convert_w(const float* wg, const float* wt,
                                                   const float* wp, const float* wW,
                                                   ushort_t* ws) {
    int idx = (blockIdx.x * 256 + threadIdx.x) * 16;   // 32 blocks
    const float* src;
    int off;
    if (idx < 32768)      { src = wg; off = idx; }
    else if (idx < 65536) { src = wt; off = idx - 32768; }
    else if (idx < 98304) { src = wp; off = idx - 65536; }
    else                  { src = wW; off = idx - 98304; }
    f16 o[16];
#pragma unroll
    for (int j = 0; j < 16; ++j) o[j] = (f16)src[off + j];
    f16* wd = (f16*)(ws + W_F);
    *(uint4*)&wd[idx]     = *(uint4*)&o[0];
    *(uint4*)&wd[idx + 8] = *(uint4*)&o[8];
}

// ------- kernel 2: fused x-transpose + theta/phi/g projections ---------------
// grid (64 ntiles, B), 1024 thr = 16 waves (4/SIMD). Phase 1: 4 c-quadrant
// passes through a f32 transpose buffer into a f16 x^T LDS tile. Phase 2:
// 16 waves cover 4 n-subs x 4 (proj,i16)-quarters.
__global__ __launch_bounds__(1024) void k_projx(const float* x, const float* bg,
        const float* bth, const float* bph, ushort_t* ws) {
    __shared__ float t[64][65];                  // 16.6 KB
    __shared__ __align__(16) f16 xt[64][280];    // 35.8 KB
    int b = blockIdx.y, n0 = blockIdx.x * 64;
    int tid = threadIdx.x;

    // ---- phase 1: 4 c-quadrants ----
    for (int q = 0; q < 4; ++q) {
        int c0 = q * 64;
        {
            int row = tid >> 4;                    // 0..63 c within quadrant
            int col4 = (tid & 15) * 4;             // n within tile
            float4 v = *(const float4*)(x + ((size_t)(b * C_ + c0 + row)) * N_ + n0 + col4);
            t[row][col4 + 0] = v.x; t[row][col4 + 1] = v.y;
            t[row][col4 + 2] = v.z; t[row][col4 + 3] = v.w;
        }
        __syncthreads();
        {
            int nl = tid & 63, cg = tid >> 6;      // 16 groups x 4 c
            f16 hv[4];
#pragma unroll
            for (int k = 0; k < 4; ++k) hv[k] = (f16)t[cg * 4 + k][nl];
            *(uint2*)&xt[nl][c0 + cg * 4] = *(uint2*)&hv[0];
        }
        __syncthreads();
    }

    // ---- phase 2: projections, 16 waves ----
    int w = tid >> 6, l = tid & 63;
    int li = l & 15, lg = l >> 4;
    int wn = (w & 3) * 16;       // n-sub
    int ip = w >> 2;             // (proj,i16) quarter: tiles ip*6 .. ip*6+5
    const f16* wf = (const f16*)(ws + W_F);

    f32x4 acc[6];
#pragma unroll
    for (int t2 = 0; t2 < 6; ++t2) acc[t2] = zero4();

#pragma unroll 2
    for (int kb = 0; kb < 8; ++kb) {
        int kc = kb * 32 + 8 * lg;
        f16x8 ah = *(const f16x8*)&xt[wn + li][kc];
#pragma unroll
        for (int t2 = 0; t2 < 6; ++t2) {
            int idx = ip * 6 + t2;               // 0..23: p = idx>>3, i16 = idx&7
            f16x8 bw = *(const f16x8*)&wf[(size_t)(idx >> 3) * 32768
                           + (size_t)(((idx & 7) * 16 + li)) * C_ + kc];
            acc[t2] = mfma16h(ah, bw, acc[t2]);
        }
    }
    f16* g3p = (f16*)(ws + G3_F);
    f16* thp = (f16*)(ws + TH_F);
    f16* php = (f16*)(ws + PH_F);
#pragma unroll
    for (int t2 = 0; t2 < 6; ++t2) {
        int idx = ip * 6 + t2;
        int p = idx >> 3;
        int i = (idx & 7) * 16 + li;
        const float* bias = (p == 0) ? bg : (p == 1) ? bth : bph;
        float bs = bias[i];
#pragma unroll
        for (int r = 0; r < 4; ++r) {
            int n = n0 + wn + 4 * lg + r;
            float v = acc[t2][r] + bs;
            if (p == 0) {
                int tq = (n >> 2) & 3;
                size_t gi = ((size_t)b * (N_ / 32) + (n >> 5)) * 4096
                          + (size_t)(tq * 128 + (i ^ (tq << 1))) * 8
                          + ((n >> 4) & 1) * 4 + (n & 3);
                g3p[gi] = (f16)v;
            } else if (p == 1)
                thp[((size_t)b * N_ + n) * I_ + i] = (f16)(v * LOG2E);
            else
                php[((size_t)b * N_ + n) * I_ + i] = (f16)v;
        }
    }
}

// ---------------- kernel 3: flash attention, 32 q/wave, KVB=32 ---------------
// grid (32 qtiles, B, splits), 256 thr = 4 waves. Lane-local defer gate: the
// cross-lane row-max reduce (2 serial ds_swizzles, ~120cyc each) runs ONLY
// when some lane's local max exceeds m+11 -- equivalent trigger to the old
// always-reduce ballot (row max = max of lane-local maxes, m row-uniform).
__global__ __launch_bounds__(256, 3) void k_attn(ushort_t* ws, float* lse, int splits) {
    __shared__ __align__(16) ushort_t smem[16384];  // 32KB: phi@0/4096, g@8192/12288
    int b = blockIdx.y, sp = blockIdx.z;
    int w = threadIdx.x >> 6, l = threadIdx.x & 63;
    int li = l & 15, lg = l >> 4;
    int q0 = blockIdx.x * 128 + w * 16;             // subtile A; subtile B at +64
    const f16* th = (const f16*)(ws + TH_F);
    const f16* ph = (const f16*)(ws + PH_F);
    const f16* g3 = (const f16*)(ws + G3_F);
    f16* yp = (f16*)(ws + YP_F) + (size_t)sp * 2097152ull;
    const f16* smf = (const f16*)smem;

    f16x8 qA[4], qB[4];
#pragma unroll
    for (int kb = 0; kb < 4; ++kb) {
        qA[kb] = *(const f16x8*)&th[((size_t)b * N_ + q0 + li) * I_ + kb * 32 + 8 * lg];
        qB[kb] = *(const f16x8*)&th[((size_t)b * N_ + q0 + 64 + li) * I_ + kb * 32 + 8 * lg];
    }

    // loop-invariant LDS read offsets (f16 units)
    int phOff[8];
#pragma unroll
    for (int kb = 0; kb < 4; ++kb) {
        int cc = ((kb * 4 + lg) ^ (li & 7)) * 8;
        phOff[kb * 2 + 0] = li * 128 + cc;
        phOff[kb * 2 + 1] = (16 + li) * 128 + cc;
    }
    int gBase = 8192 + (lg * 128 + (li ^ (lg << 1))) * 8;

    f32x4 yA[8], yB[8];
#pragma unroll
    for (int dt = 0; dt < 8; ++dt) { yA[dt] = zero4(); yB[dt] = zero4(); }
    float mA = -1e30f, lA = 0.f, mB = -1e30f, lB = 0.f;

    int beg = (sp * TOT_IT) / splits;
    int end = ((sp + 1) * TOT_IT) / splits;
    int nit = end - beg;
    int srow = l >> 4;
    const f16* srcP0 = ph + ((size_t)b * N_ + w * 8 + srow) * I_
                          + ((l & 15) ^ srow) * 8 + (size_t)beg * KVB * I_;
    const f16* srcP1 = ph + ((size_t)b * N_ + w * 8 + 4 + srow) * I_
                          + (((l & 15) ^ srow) ^ 4) * 8 + (size_t)beg * KVB * I_;
    const f16* srcG  = g3 + (size_t)b * (N_ / 32) * 4096 + w * 1024 + l * 8
                          + (size_t)beg * KVB * 128;

    // prologue: stage tile 0 into buffer 0
    gload_lds16(srcP0, smem + w * 1024);
    gload_lds16(srcP1, smem + w * 1024 + 512);
    gload_lds16(srcG,       smem + 8192 + w * 1024);
    gload_lds16(srcG + 512, smem + 8192 + w * 1024 + 512);
    srcP0 += 4096; srcP1 += 4096; srcG += 4096;
    __syncthreads();

#define ATTN_STEP(BUF, HASNEXT)                                                   \
    do {                                                                          \
        if (HASNEXT) {                                                            \
            gload_lds16(srcP0, smem + ((BUF) ^ 4096) + w * 1024);                 \
            gload_lds16(srcP1, smem + ((BUF) ^ 4096) + w * 1024 + 512);           \
            gload_lds16(srcG,       smem + 8192 + ((BUF) ^ 4096) + w * 1024);     \
            gload_lds16(srcG + 512, smem + 8192 + ((BUF) ^ 4096) + w * 1024 + 512);\
            srcP0 += 4096; srcP1 += 4096; srcG += 4096;                           \
        }                                                                         \
        f32x4 fA0 = zero4(), fA1 = zero4(), fB0 = zero4(), fB1 = zero4();         \
        __builtin_amdgcn_s_setprio(1);                                            \
        _Pragma("unroll")                                                         \
        for (int kb = 0; kb < 4; ++kb) {                                          \
            f16x8 a0 = *(const f16x8*)&smf[phOff[kb * 2 + 0] + (BUF)];            \
            f16x8 a1 = *(const f16x8*)&smf[phOff[kb * 2 + 1] + (BUF)];            \
            fA0 = mfma16h(a0, qA[kb], fA0);                                       \
            fB0 = mfma16h(a0, qB[kb], fB0);                                       \
            fA1 = mfma16h(a1, qA[kb], fA1);                                       \
            fB1 = mfma16h(a1, qB[kb], fB1);                                       \
        }                                                                         \
        __builtin_amdgcn_s_setprio(0);                                            \
        float gmA = fmaxf(fmaxf(fmaxf(fA0[0], fA0[1]), fmaxf(fA0[2], fA0[3])),    \
                          fmaxf(fmaxf(fA1[0], fA1[1]), fmaxf(fA1[2], fA1[3])));   \
        if (__ballot(gmA > mA + 11.0f)) {                                         \
            float tm = fmaxf(gmA, __shfl_xor(gmA, 16));                           \
            tm = fmaxf(tm, __shfl_xor(tm, 32));                                   \
            float mn = fmaxf(mA, tm);                                             \
            float sc = exp2_hw(mA - mn);                                          \
            lA *= sc; mA = mn;                                                    \
            float s0 = __shfl(sc, 4 * lg + 0);                                    \
            float s1 = __shfl(sc, 4 * lg + 1);                                    \
            float s2 = __shfl(sc, 4 * lg + 2);                                    \
            float s3 = __shfl(sc, 4 * lg + 3);                                    \
            _Pragma("unroll")                                                     \
            for (int dt = 0; dt < 8; ++dt) {                                      \
                yA[dt][0] *= s0; yA[dt][1] *= s1;                                 \
                yA[dt][2] *= s2; yA[dt][3] *= s3;                                 \
            }                                                                     \
        }                                                                         \
        _Pragma("unroll")                                                         \
        for (int r = 0; r < 4; ++r) {                                             \
            fA0[r] = exp2_hw(fA0[r] - mA);                                        \
            fA1[r] = exp2_hw(fA1[r] - mA);                                        \
        }                                                                         \
        lA += ((fA0[0] + fA0[1]) + (fA0[2] + fA0[3]))                             \
            + ((fA1[0] + fA1[1]) + (fA1[2] + fA1[3]));                            \
        union PU { f16x2 h2[4]; f16x8 v; };                                       \
        PU pA, pB;                                                                \
        pA.h2[0] = pkrtz(fA0[0], fA0[1]); pA.h2[1] = pkrtz(fA0[2], fA0[3]);       \
        pA.h2[2] = pkrtz(fA1[0], fA1[1]); pA.h2[3] = pkrtz(fA1[2], fA1[3]);       \
        float gmB = fmaxf(fmaxf(fmaxf(fB0[0], fB0[1]), fmaxf(fB0[2], fB0[3])),    \
                          fmaxf(fmaxf(fB1[0], fB1[1]), fmaxf(fB1[2], fB1[3])));   \
        if (__ballot(gmB > mB + 11.0f)) {                                         \
            float tm = fmaxf(gmB, __shfl_xor(gmB, 16));                           \
            tm = fmaxf(tm, __shfl_xor(tm, 32));                                   \
            float mn = fmaxf(mB, tm);                                             \
            float sc = exp2_hw(mB - mn);                                          \
            lB *= sc; mB = mn;                                                    \
            float s0 = __shfl(sc, 4 * lg + 0);                                    \
            float s1 = __shfl(sc, 4 * lg + 1);                                    \
            float s2 = __shfl(sc, 4 * lg + 2);                                    \
            float s3 = __shfl(sc, 4 * lg + 3);                                    \
            _Pragma("unroll")                                                     \
            for (int dt = 0; dt < 8; ++dt) {                                      \
                yB[dt][0] *= s0; yB[dt][1] *= s1;                                 \
                yB[dt][2] *= s2; yB[dt][3] *= s3;                                 \
            }                                                                     \
        }                                                                         \
        _Pragma("unroll")                                                         \
        for (int r = 0; r < 4; ++r) {                                             \
            fB0[r] = exp2_hw(fB0[r] - mB);                                        \
            fB1[r] = exp2_hw(fB1[r] - mB);                                        \
        }                                                                         \
        lB += ((fB0[0] + fB0[1]) + (fB0[2] + fB0[3]))                             \
            + ((fB1[0] + fB1[1]) + (fB1[2] + fB1[3]));                            \
        pB.h2[0] = pkrtz(fB0[0], fB0[1]); pB.h2[1] = pkrtz(fB0[2], fB0[3]);       \
        pB.h2[2] = pkrtz(fB1[0], fB1[1]); pB.h2[3] = pkrtz(fB1[2], fB1[3]);       \
        __builtin_amdgcn_s_setprio(1);                                            \
        _Pragma("unroll")                                                         \
        for (int dt = 0; dt < 8; ++dt) {                                          \
            f16x8 gv = *(const f16x8*)&smf[gBase + dt * 128 + (BUF)];             \
            yA[dt] = mfma16h(pA.v, gv, yA[dt]);                                   \
            yB[dt] = mfma16h(pB.v, gv, yB[dt]);                                   \
        }                                                                         \
        __builtin_amdgcn_s_setprio(0);                                            \
        __syncthreads();                                                          \
    } while (0)

    int it = 0;
    while (it + 2 <= nit) {
        ATTN_STEP(0, (it + 1 < nit));
        ATTN_STEP(4096, (it + 2 < nit));
        it += 2;
    }
    if (it < nit) ATTN_STEP(0, false);
#undef ATTN_STEP

    // epilogue: cross-lane sum (deferred), normalized partials + base-2 lse
    lA += __shfl_xor(lA, 16); lA += __shfl_xor(lA, 32);
    lB += __shfl_xor(lB, 16); lB += __shfl_xor(lB, 32);
    {
        float inv = 1.0f / lA;
        float i0 = __shfl(inv, 4 * lg + 0);
        float i1 = __shfl(inv, 4 * lg + 1);
        float i2 = __shfl(inv, 4 * lg + 2);
        float i3 = __shfl(inv, 4 * lg + 3);
#pragma unroll
        for (int dt = 0; dt < 8; ++dt) {
            size_t base = ((size_t)b * N_ + q0 + 4 * lg) * I_ + dt * 16 + li;
            yp[base]          = (f16)(yA[dt][0] * i0);
            yp[base + I_]     = (f16)(yA[dt][1] * i1);
            yp[base + 2 * I_] = (f16)(yA[dt][2] * i2);
            yp[base + 3 * I_] = (f16)(yA[dt][3] * i3);
        }
    }
    {
        float inv = 1.0f / lB;
        float i0 = __shfl(inv, 4 * lg + 0);
        float i1 = __shfl(inv, 4 * lg + 1);
        float i2 = __shfl(inv, 4 * lg + 2);
        float i3 = __shfl(inv, 4 * lg + 3);
#pragma unroll
        for (int dt = 0; dt < 8; ++dt) {
            size_t base = ((size_t)b * N_ + q0 + 64 + 4 * lg) * I_ + dt * 16 + li;
            yp[base]          = (f16)(yB[dt][0] * i0);
            yp[base + I_]     = (f16)(yB[dt][1] * i1);
            yp[base + 2 * I_] = (f16)(yB[dt][2] * i2);
            yp[base + 3 * I_] = (f16)(yB[dt][3] * i3);
        }
    }
    if (l < 16) {
        lse[((size_t)sp * B_ + b) * N_ + q0 + l]      = mA + log2_hw(lA);
        lse[((size_t)sp * B_ + b) * N_ + q0 + 64 + l] = mB + log2_hw(lB);
    }
}

// ------- kernel 4: fused split-merge + output projection + residual ----------
// grid (64 ntiles, B), 1024 thr = 16 waves. Phase 1: merge partials into LDS.
// Phase 2: 16 waves cover 4 c-quarters x 4 n-subs.
__global__ __launch_bounds__(1024) void k_out(const float* x, const float* bW,
        const ushort_t* ws, const float* lse, float* out, int splits) {
    __shared__ __align__(16) f16 ylds[64 * 136];
    int b = blockIdx.y, n0 = blockIdx.x * 64;
    int tid = threadIdx.x;
    {
        int nn = tid >> 4, ig = tid & 15;          // 8 f16 per thread
        size_t lrow = (size_t)b * N_ + n0 + nn;
        float mx = -1e30f;
        for (int s = 0; s < splits; ++s)
            mx = fmaxf(mx, lse[(size_t)s * (B_ * N_) + lrow]);
        float sum = 0.f;
        for (int s = 0; s < splits; ++s)
            sum += exp2_hw(lse[(size_t)s * (B_ * N_) + lrow] - mx);
        float inv = 1.0f / sum;
        float acc[8];
#pragma unroll
        for (int j = 0; j < 8; ++j) acc[j] = 0.f;
        for (int s = 0; s < splits; ++s) {
            float wg = exp2_hw(lse[(size_t)s * (B_ * N_) + lrow] - mx) * inv;
            const f16* p = (const f16*)(ws + YP_F) + (size_t)s * 2097152ull
                         + lrow * I_ + ig * 8;
            f16x8 v0 = *(const f16x8*)p;
#pragma unroll
            for (int j = 0; j < 8; ++j) acc[j] += wg * (float)v0[j];
        }
        f16 o[8];
#pragma unroll
        for (int j = 0; j < 8; ++j) o[j] = (f16)acc[j];
        *(uint4*)&ylds[nn * 136 + ig * 8] = *(uint4*)&o[0];
    }
    __syncthreads();

    int w = tid >> 6, l = tid & 63;
    int li = l & 15, lg = l >> 4;
    int cw = (w >> 2) * 64, nsub = (w & 3) * 16;
    const f16* wfp = (const f16*)(ws + W_F) + 98304;   // w_W [256][128] f16

    f32x4 acc2[4];
#pragma unroll
    for (int mm = 0; mm < 4; ++mm) acc2[mm] = zero4();

#pragma unroll 2
    for (int kb = 0; kb < 4; ++kb) {
        int kc = kb * 32 + 8 * lg;
        f16x8 byv = *(const f16x8*)&ylds[(nsub + li) * 136 + kc];
#pragma unroll
        for (int mm = 0; mm < 4; ++mm) {
            f16x8 a = *(const f16x8*)&wfp[(size_t)(cw + mm * 16 + li) * I_ + kc];
            acc2[mm] = mfma16h(a, byv, acc2[mm]);
        }
    }
#pragma unroll
    for (int mm = 0; mm < 4; ++mm)
#pragma unroll
        for (int r = 0; r < 4; ++r) {
            int c = cw + mm * 16 + lg * 4 + r;
            int nn = n0 + nsub + li;
            size_t xi = ((size_t)b * C_ + c) * N_ + nn;
            out[xi] = acc2[mm][r] + bW[c] + x[xi];
        }
}

extern "C" void kernel_launch(void* const* d_in, const int* in_sizes, int n_in,
                              void* d_out, int out_size, void* d_ws, size_t ws_size,
                              hipStream_t stream) {
    const float* x  = (const float*)d_in[0];
    const float* wg = (const float*)d_in[1];
    const float* bg = (const float*)d_in[2];
    const float* wt = (const float*)d_in[3];
    const float* bt = (const float*)d_in[4];
    const float* wp = (const float*)d_in[5];
    const float* bp = (const float*)d_in[6];
    const float* wW = (const float*)d_in[7];
    const float* bW = (const float*)d_in[8];
    ushort_t* ws = (ushort_t*)d_ws;
    float* out = (float*)d_out;

    // footprint(S) = 2*(YP_F + S*2097152) + S*65536 bytes
    int splits = (ws_size >= 46923776ull) ? 8
               : (ws_size >= 42663936ull) ? 7
               : (ws_size >= 38404096ull) ? 6 : 4;
    size_t lse_off = 2ull * (YP_F + (size_t)splits * 2097152ull);
    float* lse = (float*)((char*)d_ws + lse_off);

    k_convert_w<<<32, 256, 0, stream>>>(wg, wt, wp, wW, ws);
    k_projx<<<dim3(64, 4), 1024, 0, stream>>>(x, bg, bt, bp, ws);
    k_attn<<<dim3(32, 4, splits), 256, 0, stream>>>(ws, lse, splits);
    k_out<<<dim3(64, 4), 1024, 0, stream>>>(x, bW, ws, lse, out, splits);
}

// Round 15
// 104.681 us; speedup vs baseline: 1.0251x; 1.0251x over previous
//
#include <hip/hip_runtime.h>

typedef unsigned short ushort_t;
typedef unsigned int uint_t;
typedef _Float16 f16;
typedef __attribute__((ext_vector_type(8))) _Float16 f16x8;
typedef __attribute__((ext_vector_type(2))) _Float16 f16x2;
typedef __attribute__((ext_vector_type(4))) float f32x4;

#define B_ 4
#define C_ 256
#define I_ 128
#define N_ 4096
#define KVB 32
#define TOT_IT (N_ / KVB)     // 128
#define LOG2E 1.44269504f

// ws layout in 2-byte units (x_t eliminated -- transpose fused into proj)
#define W_F  0ull             // f16 weights: wg@0 wt@32768 wp@65536 wW@98304 (131072)
#define TH_F 131072ull        // f16 theta (pre-scaled by log2e) [B][N][I] (2M)
#define PH_F 2228224ull       // f16 phi [B][N][I] (2M)
#define G3_F 4325376ull       // f16 g, PV-tile layout [B][N/32][4][I][8], lg-XOR swz
#define YP_F 6422528ull       // f16 partials [S][B][N][I] (2,097,152 each)
// lse (f32, base-2) at byte offset 2*(YP_F + S*2097152)

__device__ __forceinline__ float exp2_hw(float x) { return __builtin_amdgcn_exp2f(x); }
__device__ __forceinline__ float log2_hw(float x) { return __builtin_amdgcn_logf(x); }

__device__ __forceinline__ f16x2 pkrtz(float a, float b) {
    auto r = __builtin_amdgcn_cvt_pkrtz(a, b);
    f16x2 o;
    __builtin_memcpy(&o, &r, sizeof(o));
    return o;
}
__device__ __forceinline__ f32x4 mfma16h(f16x8 a, f16x8 b, f32x4 c) {
    return __builtin_amdgcn_mfma_f32_16x16x32_f16(a, b, c, 0, 0, 0);
}
__device__ __forceinline__ f32x4 zero4() { f32x4 z = {0.f, 0.f, 0.f, 0.f}; return z; }
__device__ __forceinline__ void gload_lds16(const void* g, void* lds) {
    __builtin_amdgcn_global_load_lds(
        (const __attribute__((address_space(1))) void*)g,
        (__attribute__((address_space(3))) void*)lds, 16, 0, 0);
}

// ---------------- kernel 1: convert weights to f16 ---------------------------
__global__ __launch_bounds__(256) void k_convert_w(const float* wg, const float* wt,
                                                   const float* wp, const float* wW,
                                                   ushort_t* ws) {
    int idx = (blockIdx.x * 256 + threadIdx.x) * 16;   // 32 blocks
    const float* src;
    int off;
    if (idx < 32768)      { src = wg; off = idx; }
    else if (idx < 65536) { src = wt; off = idx - 32768; }
    else if (idx < 98304) { src = wp; off = idx - 65536; }
    else                  { src = wW; off = idx - 98304; }
    f16 o[16];
#pragma unroll
    for (int j = 0; j < 16; ++j) o[j] = (f16)src[off + j];
    f16* wd = (f16*)(ws + W_F);
    *(uint4*)&wd[idx]     = *(uint4*)&o[0];
    *(uint4*)&wd[idx + 8] = *(uint4*)&o[8];
}

// ------- kernel 2: fused x-transpose + theta/phi/g projections ---------------
// grid (64 ntiles, B), 512 thr = 8 waves. Phase 1: stage x[b][0..255][n0..n0+63]
// into LDS as f16 x^T tile (4 quadrant passes through a f32 transpose buffer).
// Phase 2: 3 projections via MFMA, A-frags from LDS x^T, B-frags = f16 weights.
__global__ __launch_bounds__(512) void k_projx(const float* x, const float* bg,
        const float* bth, const float* bph, ushort_t* ws) {
    __shared__ float t[64][65];                  // 16.6 KB
    __shared__ __align__(16) f16 xt[64][280];    // 35.8 KB (stride 280: 16B-aligned,
                                                 //  2-way-max bank aliasing)
    int b = blockIdx.y, n0 = blockIdx.x * 64;
    int tid = threadIdx.x;

    // ---- phase 1: 4 c-quadrants ----
    for (int q = 0; q < 4; ++q) {
        int c0 = q * 64;
#pragma unroll
        for (int p = 0; p < 2; ++p) {
            int row = p * 32 + (tid >> 4);         // c within quadrant
            int col4 = (tid & 15) * 4;             // n within tile
            float4 v = *(const float4*)(x + ((size_t)(b * C_ + c0 + row)) * N_ + n0 + col4);
            t[row][col4 + 0] = v.x; t[row][col4 + 1] = v.y;
            t[row][col4 + 2] = v.z; t[row][col4 + 3] = v.w;
        }
        __syncthreads();
        {
            int nl = tid & 63, cg = tid >> 6;      // 8 c per thread
            f16 hv[8];
#pragma unroll
            for (int k = 0; k < 8; ++k) hv[k] = (f16)t[cg * 8 + k][nl];
            *(uint4*)&xt[nl][c0 + cg * 8] = *(uint4*)&hv[0];
        }
        __syncthreads();
    }

    // ---- phase 2: projections ----
    int w = tid >> 6, l = tid & 63;
    int li = l & 15, lg = l >> 4;
    int wn = (w & 3) * 16;
    int ihb = (w >> 2) * 4;
    const f16* wf = (const f16*)(ws + W_F);

    f32x4 acc[3][4];
#pragma unroll
    for (int p = 0; p < 3; ++p)
#pragma unroll
        for (int t2 = 0; t2 < 4; ++t2) acc[p][t2] = zero4();

#pragma unroll 2
    for (int kb = 0; kb < 8; ++kb) {
        int kc = kb * 32 + 8 * lg;
        f16x8 ah = *(const f16x8*)&xt[wn + li][kc];
#pragma unroll
        for (int p = 0; p < 3; ++p)
#pragma unroll
            for (int t2 = 0; t2 < 4; ++t2) {
                f16x8 bw = *(const f16x8*)&wf[(size_t)p * 32768
                               + (size_t)((ihb + t2) * 16 + li) * C_ + kc];
                acc[p][t2] = mfma16h(ah, bw, acc[p][t2]);
            }
    }
    f16* g3p = (f16*)(ws + G3_F);
    f16* thp = (f16*)(ws + TH_F);
    f16* php = (f16*)(ws + PH_F);
#pragma unroll
    for (int p = 0; p < 3; ++p) {
        const float* bias = (p == 0) ? bg : (p == 1) ? bth : bph;
#pragma unroll
        for (int t2 = 0; t2 < 4; ++t2) {
            int i = (ihb + t2) * 16 + li;
            float bs = bias[i];
#pragma unroll
            for (int r = 0; r < 4; ++r) {
                int n = n0 + wn + 4 * lg + r;
                float v = acc[p][t2][r] + bs;
                if (p == 0) {
                    int tq = (n >> 2) & 3;
                    size_t gi = ((size_t)b * (N_ / 32) + (n >> 5)) * 4096
                              + (size_t)(tq * 128 + (i ^ (tq << 1))) * 8
                              + ((n >> 4) & 1) * 4 + (n & 3);
                    g3p[gi] = (f16)v;
                } else if (p == 1)
                    thp[((size_t)b * N_ + n) * I_ + i] = (f16)(v * LOG2E);
                else
                    php[((size_t)b * N_ + n) * I_ + i] = (f16)v;
            }
        }
    }
}

// ---------------- kernel 3: flash attention, 32 q/wave, KVB=32 ---------------
// grid (32 qtiles, B, splits), 256 thr = 4 waves. Loop unrolled x2 with literal
// LDS buffer offsets; LDS read offsets hoisted to loop-invariant registers.
// launch_bounds (256,3): VGPR demand ~130; forcing 4 waves/EU (round 10)
// capped VGPRs at 64 -> scratch spills -> FETCH 250MB, 2x slowdown.
__global__ __launch_bounds__(256, 3) void k_attn(ushort_t* ws, float* lse, int splits) {
    __shared__ __align__(16) ushort_t smem[16384];  // 32KB: phi@0/4096, g@8192/12288
    int b = blockIdx.y, sp = blockIdx.z;
    int w = threadIdx.x >> 6, l = threadIdx.x & 63;
    int li = l & 15, lg = l >> 4;
    int q0 = blockIdx.x * 128 + w * 16;             // subtile A; subtile B at +64
    const f16* th = (const f16*)(ws + TH_F);
    const f16* ph = (const f16*)(ws + PH_F);
    const f16* g3 = (const f16*)(ws + G3_F);
    f16* yp = (f16*)(ws + YP_F) + (size_t)sp * 2097152ull;
    const f16* smf = (const f16*)smem;

    f16x8 qA[4], qB[4];
#pragma unroll
    for (int kb = 0; kb < 4; ++kb) {
        qA[kb] = *(const f16x8*)&th[((size_t)b * N_ + q0 + li) * I_ + kb * 32 + 8 * lg];
        qB[kb] = *(const f16x8*)&th[((size_t)b * N_ + q0 + 64 + li) * I_ + kb * 32 + 8 * lg];
    }

    // loop-invariant LDS read offsets (f16 units)
    int phOff[8];
#pragma unroll
    for (int kb = 0; kb < 4; ++kb) {
        int cc = ((kb * 4 + lg) ^ (li & 7)) * 8;
        phOff[kb * 2 + 0] = li * 128 + cc;
        phOff[kb * 2 + 1] = (16 + li) * 128 + cc;
    }
    // g: (dt*16+li)^(lg<<1) == dt*16 + (li^(lg<<1))  ->  base + dt*128
    int gBase = 8192 + (lg * 128 + (li ^ (lg << 1))) * 8;

    f32x4 yA[8], yB[8];
#pragma unroll
    for (int dt = 0; dt < 8; ++dt) { yA[dt] = zero4(); yB[dt] = zero4(); }
    float mA = -1e30f, lA = 0.f, mB = -1e30f, lB = 0.f;

    int beg = (sp * TOT_IT) / splits;
    int end = ((sp + 1) * TOT_IT) / splits;
    int nit = end - beg;
    int srow = l >> 4;
    const f16* srcP0 = ph + ((size_t)b * N_ + w * 8 + srow) * I_
                          + ((l & 15) ^ srow) * 8 + (size_t)beg * KVB * I_;
    const f16* srcP1 = ph + ((size_t)b * N_ + w * 8 + 4 + srow) * I_
                          + (((l & 15) ^ srow) ^ 4) * 8 + (size_t)beg * KVB * I_;
    const f16* srcG  = g3 + (size_t)b * (N_ / 32) * 4096 + w * 1024 + l * 8
                          + (size_t)beg * KVB * 128;

    // prologue: stage tile 0 into buffer 0
    gload_lds16(srcP0, smem + w * 1024);
    gload_lds16(srcP1, smem + w * 1024 + 512);
    gload_lds16(srcG,       smem + 8192 + w * 1024);
    gload_lds16(srcG + 512, smem + 8192 + w * 1024 + 512);
    srcP0 += 4096; srcP1 += 4096; srcG += 4096;
    __syncthreads();

#define ATTN_STEP(BUF, HASNEXT)                                                   \
    do {                                                                          \
        if (HASNEXT) {                                                            \
            gload_lds16(srcP0, smem + ((BUF) ^ 4096) + w * 1024);                 \
            gload_lds16(srcP1, smem + ((BUF) ^ 4096) + w * 1024 + 512);           \
            gload_lds16(srcG,       smem + 8192 + ((BUF) ^ 4096) + w * 1024);     \
            gload_lds16(srcG + 512, smem + 8192 + ((BUF) ^ 4096) + w * 1024 + 512);\
            srcP0 += 4096; srcP1 += 4096; srcG += 4096;                           \
        }                                                                         \
        f32x4 fA0 = zero4(), fA1 = zero4(), fB0 = zero4(), fB1 = zero4();         \
        __builtin_amdgcn_s_setprio(1);                                            \
        _Pragma("unroll")                                                         \
        for (int kb = 0; kb < 4; ++kb) {                                          \
            f16x8 a0 = *(const f16x8*)&smf[phOff[kb * 2 + 0] + (BUF)];            \
            f16x8 a1 = *(const f16x8*)&smf[phOff[kb * 2 + 1] + (BUF)];            \
            fA0 = mfma16h(a0, qA[kb], fA0);                                       \
            fB0 = mfma16h(a0, qB[kb], fB0);                                       \
            fA1 = mfma16h(a1, qA[kb], fA1);                                       \
            fB1 = mfma16h(a1, qB[kb], fB1);                                       \
        }                                                                         \
        __builtin_amdgcn_s_setprio(0);                                            \
        float tmA = fmaxf(fmaxf(fmaxf(fA0[0], fA0[1]), fmaxf(fA0[2], fA0[3])),    \
                          fmaxf(fmaxf(fA1[0], fA1[1]), fmaxf(fA1[2], fA1[3])));   \
        tmA = fmaxf(tmA, __shfl_xor(tmA, 16));                                    \
        tmA = fmaxf(tmA, __shfl_xor(tmA, 32));                                    \
        if (__ballot(tmA > mA + 11.0f)) {                                         \
            float mn = fmaxf(mA, tmA);                                            \
            float sc = exp2_hw(mA - mn);                                          \
            lA *= sc; mA = mn;                                                    \
            float s0 = __shfl(sc, 4 * lg + 0);                                    \
            float s1 = __shfl(sc, 4 * lg + 1);                                    \
            float s2 = __shfl(sc, 4 * lg + 2);                                    \
            float s3 = __shfl(sc, 4 * lg + 3);                                    \
            _Pragma("unroll")                                                     \
            for (int dt = 0; dt < 8; ++dt) {                                      \
                yA[dt][0] *= s0; yA[dt][1] *= s1;                                 \
                yA[dt][2] *= s2; yA[dt][3] *= s3;                                 \
            }                                                                     \
        }                                                                         \
        _Pragma("unroll")                                                         \
        for (int r = 0; r < 4; ++r) {                                             \
            fA0[r] = exp2_hw(fA0[r] - mA);                                        \
            fA1[r] = exp2_hw(fA1[r] - mA);                                        \
        }                                                                         \
        lA += ((fA0[0] + fA0[1]) + (fA0[2] + fA0[3]))                             \
            + ((fA1[0] + fA1[1]) + (fA1[2] + fA1[3]));                            \
        union PU { f16x2 h2[4]; f16x8 v; };                                       \
        PU pA, pB;                                                                \
        pA.h2[0] = pkrtz(fA0[0], fA0[1]); pA.h2[1] = pkrtz(fA0[2], fA0[3]);       \
        pA.h2[2] = pkrtz(fA1[0], fA1[1]); pA.h2[3] = pkrtz(fA1[2], fA1[3]);       \
        float tmB = fmaxf(fmaxf(fmaxf(fB0[0], fB0[1]), fmaxf(fB0[2], fB0[3])),    \
                          fmaxf(fmaxf(fB1[0], fB1[1]), fmaxf(fB1[2], fB1[3])));   \
        tmB = fmaxf(tmB, __shfl_xor(tmB, 16));                                    \
        tmB = fmaxf(tmB, __shfl_xor(tmB, 32));                                    \
        if (__ballot(tmB > mB + 11.0f)) {                                         \
            float mn = fmaxf(mB, tmB);                                            \
            float sc = exp2_hw(mB - mn);                                          \
            lB *= sc; mB = mn;                                                    \
            float s0 = __shfl(sc, 4 * lg + 0);                                    \
            float s1 = __shfl(sc, 4 * lg + 1);                                    \
            float s2 = __shfl(sc, 4 * lg + 2);                                    \
            float s3 = __shfl(sc, 4 * lg + 3);                                    \
            _Pragma("unroll")                                                     \
            for (int dt = 0; dt < 8; ++dt) {                                      \
                yB[dt][0] *= s0; yB[dt][1] *= s1;                                 \
                yB[dt][2] *= s2; yB[dt][3] *= s3;                                 \
            }                                                                     \
        }                                                                         \
        _Pragma("unroll")                                                         \
        for (int r = 0; r < 4; ++r) {                                             \
            fB0[r] = exp2_hw(fB0[r] - mB);                                        \
            fB1[r] = exp2_hw(fB1[r] - mB);                                        \
        }                                                                         \
        lB += ((fB0[0] + fB0[1]) + (fB0[2] + fB0[3]))                             \
            + ((fB1[0] + fB1[1]) + (fB1[2] + fB1[3]));                            \
        pB.h2[0] = pkrtz(fB0[0], fB0[1]); pB.h2[1] = pkrtz(fB0[2], fB0[3]);       \
        pB.h2[2] = pkrtz(fB1[0], fB1[1]); pB.h2[3] = pkrtz(fB1[2], fB1[3]);       \
        __builtin_amdgcn_s_setprio(1);                                            \
        _Pragma("unroll")                                                         \
        for (int dt = 0; dt < 8; ++dt) {                                          \
            f16x8 gv = *(const f16x8*)&smf[gBase + dt * 128 + (BUF)];             \
            yA[dt] = mfma16h(pA.v, gv, yA[dt]);                                   \
            yB[dt] = mfma16h(pB.v, gv, yB[dt]);                                   \
        }                                                                         \
        __builtin_amdgcn_s_setprio(0);                                            \
        __syncthreads();                                                          \
    } while (0)

    int it = 0;
    while (it + 2 <= nit) {
        ATTN_STEP(0, (it + 1 < nit));
        ATTN_STEP(4096, (it + 2 < nit));
        it += 2;
    }
    if (it < nit) ATTN_STEP(0, false);
#undef ATTN_STEP

    // epilogue: cross-lane sum (deferred), normalized partials + base-2 lse
    lA += __shfl_xor(lA, 16); lA += __shfl_xor(lA, 32);
    lB += __shfl_xor(lB, 16); lB += __shfl_xor(lB, 32);
    {
        float inv = 1.0f / lA;
        float i0 = __shfl(inv, 4 * lg + 0);
        float i1 = __shfl(inv, 4 * lg + 1);
        float i2 = __shfl(inv, 4 * lg + 2);
        float i3 = __shfl(inv, 4 * lg + 3);
#pragma unroll
        for (int dt = 0; dt < 8; ++dt) {
            size_t base = ((size_t)b * N_ + q0 + 4 * lg) * I_ + dt * 16 + li;
            yp[base]          = (f16)(yA[dt][0] * i0);
            yp[base + I_]     = (f16)(yA[dt][1] * i1);
            yp[base + 2 * I_] = (f16)(yA[dt][2] * i2);
            yp[base + 3 * I_] = (f16)(yA[dt][3] * i3);
        }
    }
    {
        float inv = 1.0f / lB;
        float i0 = __shfl(inv, 4 * lg + 0);
        float i1 = __shfl(inv, 4 * lg + 1);
        float i2 = __shfl(inv, 4 * lg + 2);
        float i3 = __shfl(inv, 4 * lg + 3);
#pragma unroll
        for (int dt = 0; dt < 8; ++dt) {
            size_t base = ((size_t)b * N_ + q0 + 64 + 4 * lg) * I_ + dt * 16 + li;
            yp[base]          = (f16)(yB[dt][0] * i0);
            yp[base + I_]     = (f16)(yB[dt][1] * i1);
            yp[base + 2 * I_] = (f16)(yB[dt][2] * i2);
            yp[base + 3 * I_] = (f16)(yB[dt][3] * i3);
        }
    }
    if (l < 16) {
        lse[((size_t)sp * B_ + b) * N_ + q0 + l]      = mA + log2_hw(lA);
        lse[((size_t)sp * B_ + b) * N_ + q0 + 64 + l] = mB + log2_hw(lB);
    }
}

// ------- kernel 4: fused split-merge + output projection + residual ----------
__global__ __launch_bounds__(512) void k_out(const float* x, const float* bW,
        const ushort_t* ws, const float* lse, float* out, int splits) {
    __shared__ __align__(16) f16 ylds[64 * 136];
    int b = blockIdx.y, n0 = blockIdx.x * 64;
    int tid = threadIdx.x;
    {
        int nn = tid >> 3, ig = tid & 7;
        size_t lrow = (size_t)b * N_ + n0 + nn;
        float mx = -1e30f;
        for (int s = 0; s < splits; ++s)
            mx = fmaxf(mx, lse[(size_t)s * (B_ * N_) + lrow]);
        float sum = 0.f;
        for (int s = 0; s < splits; ++s)
            sum += exp2_hw(lse[(size_t)s * (B_ * N_) + lrow] - mx);
        float inv = 1.0f / sum;
        float acc[16];
#pragma unroll
        for (int j = 0; j < 16; ++j) acc[j] = 0.f;
        for (int s = 0; s < splits; ++s) {
            float wg = exp2_hw(lse[(size_t)s * (B_ * N_) + lrow] - mx) * inv;
            const f16* p = (const f16*)(ws + YP_F) + (size_t)s * 2097152ull
                         + lrow * I_ + ig * 16;
            f16x8 v0 = *(const f16x8*)p;
            f16x8 v1 = *(const f16x8*)(p + 8);
#pragma unroll
            for (int j = 0; j < 8; ++j) {
                acc[j]     += wg * (float)v0[j];
                acc[8 + j] += wg * (float)v1[j];
            }
        }
        f16 o[16];
#pragma unroll
        for (int j = 0; j < 16; ++j) o[j] = (f16)acc[j];
        *(uint4*)&ylds[nn * 136 + ig * 16]     = *(uint4*)&o[0];
        *(uint4*)&ylds[nn * 136 + ig * 16 + 8] = *(uint4*)&o[8];
    }
    __syncthreads();

    int w = tid >> 6, l = tid & 63;
    int li = l & 15, lg = l >> 4;
    int cw = (w >> 1) * 64, nh = (w & 1) * 32;
    const f16* wfp = (const f16*)(ws + W_F) + 98304;   // w_W [256][128] f16

    f32x4 acc2[4][2];
#pragma unroll
    for (int mm = 0; mm < 4; ++mm)
#pragma unroll
        for (int n = 0; n < 2; ++n) acc2[mm][n] = zero4();

#pragma unroll 2
    for (int kb = 0; kb < 4; ++kb) {
        int kc = kb * 32 + 8 * lg;
        f16x8 a[4], byv[2];
#pragma unroll
        for (int mm = 0; mm < 4; ++mm)
            a[mm] = *(const f16x8*)&wfp[(size_t)(cw + mm * 16 + li) * I_ + kc];
#pragma unroll
        for (int n = 0; n < 2; ++n)
            byv[n] = *(const f16x8*)&ylds[(nh + n * 16 + li) * 136 + kc];
#pragma unroll
        for (int mm = 0; mm < 4; ++mm)
#pragma unroll
            for (int n = 0; n < 2; ++n)
                acc2[mm][n] = mfma16h(a[mm], byv[n], acc2[mm][n]);
    }
#pragma unroll
    for (int mm = 0; mm < 4; ++mm)
#pragma unroll
        for (int n = 0; n < 2; ++n)
#pragma unroll
            for (int r = 0; r < 4; ++r) {
                int c = cw + mm * 16 + lg * 4 + r;
                int nn = n0 + nh + n * 16 + li;
                size_t xi = ((size_t)b * C_ + c) * N_ + nn;
                out[xi] = acc2[mm][n][r] + bW[c] + x[xi];
            }
}

extern "C" void kernel_launch(void* const* d_in, const int* in_sizes, int n_in,
                              void* d_out, int out_size, void* d_ws, size_t ws_size,
                              hipStream_t stream) {
    const float* x  = (const float*)d_in[0];
    const float* wg = (const float*)d_in[1];
    const float* bg = (const float*)d_in[2];
    const float* wt = (const float*)d_in[3];
    const float* bt = (const float*)d_in[4];
    const float* wp = (const float*)d_in[5];
    const float* bp = (const float*)d_in[6];
    const float* wW = (const float*)d_in[7];
    const float* bW = (const float*)d_in[8];
    ushort_t* ws = (ushort_t*)d_ws;
    float* out = (float*)d_out;

    // footprint(S) = 2*(YP_F + S*2097152) + S*65536 bytes
    int splits = (ws_size >= 46923776ull) ? 8
               : (ws_size >= 42663936ull) ? 7
               : (ws_size >= 38404096ull) ? 6 : 4;
    size_t lse_off = 2ull * (YP_F + (size_t)splits * 2097152ull);
    float* lse = (float*)((char*)d_ws + lse_off);

    k_convert_w<<<32, 256, 0, stream>>>(wg, wt, wp, wW, ws);
    k_projx<<<dim3(64, 4), 512, 0, stream>>>(x, bg, bt, bp, ws);
    k_attn<<<dim3(32, 4, splits), 256, 0, stream>>>(ws, lse, splits);
    k_out<<<dim3(64, 4), 512, 0, stream>>>(x, bW, ws, lse, out, splits);
}

// Round 16
// 104.210 us; speedup vs baseline: 1.0298x; 1.0045x over previous
//
#include <hip/hip_runtime.h>

typedef unsigned short ushort_t;
typedef unsigned int uint_t;
typedef _Float16 f16;
typedef __attribute__((ext_vector_type(8))) _Float16 f16x8;
typedef __attribute__((ext_vector_type(2))) _Float16 f16x2;
typedef __attribute__((ext_vector_type(4))) float f32x4;

#define B_ 4
#define C_ 256
#define I_ 128
#define N_ 4096
#define KVB 32
#define TOT_IT (N_ / KVB)     // 128
#define LOG2E 1.44269504f

// ws layout in 2-byte units (x_t eliminated -- transpose fused into proj)
#define W_F  0ull             // f16 weights: wg@0 wt@32768 wp@65536 wW@98304 (131072)
#define TH_F 131072ull        // f16 theta (pre-scaled by log2e) [B][N][I] (2M)
#define PH_F 2228224ull       // f16 phi [B][N][I] (2M)
#define G3_F 4325376ull       // f16 g, PV-tile layout [B][N/32][4][I][8], lg-XOR swz
#define YP_F 6422528ull       // f16 partials [S][B][N][I] (2,097,152 each)
// lse (f32, base-2) at byte offset 2*(YP_F + S*2097152)

__device__ __forceinline__ float exp2_hw(float x) { return __builtin_amdgcn_exp2f(x); }
__device__ __forceinline__ float log2_hw(float x) { return __builtin_amdgcn_logf(x); }

__device__ __forceinline__ f16x2 pkrtz(float a, float b) {
    auto r = __builtin_amdgcn_cvt_pkrtz(a, b);
    f16x2 o;
    __builtin_memcpy(&o, &r, sizeof(o));
    return o;
}
__device__ __forceinline__ f32x4 mfma16h(f16x8 a, f16x8 b, f32x4 c) {
    return __builtin_amdgcn_mfma_f32_16x16x32_f16(a, b, c, 0, 0, 0);
}
__device__ __forceinline__ f32x4 zero4() { f32x4 z = {0.f, 0.f, 0.f, 0.f}; return z; }
__device__ __forceinline__ void gload_lds16(const void* g, void* lds) {
    __builtin_amdgcn_global_load_lds(
        (const __attribute__((address_space(1))) void*)g,
        (__attribute__((address_space(3))) void*)lds, 16, 0, 0);
}

// ---------------- kernel 1: convert weights to f16 ---------------------------
__global__ __launch_bounds__(256) void k_convert_w(const float* wg, const float* wt,
                                                   const float* wp, const float* wW,
                                                   ushort_t* ws) {
    int idx = (blockIdx.x * 256 + threadIdx.x) * 16;   // 32 blocks
    const float* src;
    int off;
    if (idx < 32768)      { src = wg; off = idx; }
    else if (idx < 65536) { src = wt; off = idx - 32768; }
    else if (idx < 98304) { src = wp; off = idx - 65536; }
    else                  { src = wW; off = idx - 98304; }
    f16 o[16];
#pragma unroll
    for (int j = 0; j < 16; ++j) o[j] = (f16)src[off + j];
    f16* wd = (f16*)(ws + W_F);
    *(uint4*)&wd[idx]     = *(uint4*)&o[0];
    *(uint4*)&wd[idx + 8] = *(uint4*)&o[8];
}

// ------- kernel 2: fused x-transpose + theta/phi/g projections ---------------
// grid (64 ntiles, B), 512 thr = 8 waves. Phase 1: stage x[b][0..255][n0..n0+63]
// into LDS as f16 x^T tile (4 quadrant passes through a f32 transpose buffer).
// Phase 2: 3 projections via MFMA, A-frags from LDS x^T, B-frags = f16 weights.
__global__ __launch_bounds__(512) void k_projx(const float* x, const float* bg,
        const float* bth, const float* bph, ushort_t* ws) {
    __shared__ float t[64][65];                  // 16.6 KB
    __shared__ __align__(16) f16 xt[64][280];    // 35.8 KB (stride 280: 16B-aligned,
                                                 //  2-way-max bank aliasing)
    int b = blockIdx.y, n0 = blockIdx.x * 64;
    int tid = threadIdx.x;

    // ---- phase 1: 4 c-quadrants ----
    for (int q = 0; q < 4; ++q) {
        int c0 = q * 64;
#pragma unroll
        for (int p = 0; p < 2; ++p) {
            int row = p * 32 + (tid >> 4);         // c within quadrant
            int col4 = (tid & 15) * 4;             // n within tile
            float4 v = *(const float4*)(x + ((size_t)(b * C_ + c0 + row)) * N_ + n0 + col4);
            t[row][col4 + 0] = v.x; t[row][col4 + 1] = v.y;
            t[row][col4 + 2] = v.z; t[row][col4 + 3] = v.w;
        }
        __syncthreads();
        {
            int nl = tid & 63, cg = tid >> 6;      // 8 c per thread
            f16 hv[8];
#pragma unroll
            for (int k = 0; k < 8; ++k) hv[k] = (f16)t[cg * 8 + k][nl];
            *(uint4*)&xt[nl][c0 + cg * 8] = *(uint4*)&hv[0];
        }
        __syncthreads();
    }

    // ---- phase 2: projections ----
    int w = tid >> 6, l = tid & 63;
    int li = l & 15, lg = l >> 4;
    int wn = (w & 3) * 16;
    int ihb = (w >> 2) * 4;
    const f16* wf = (const f16*)(ws + W_F);

    f32x4 acc[3][4];
#pragma unroll
    for (int p = 0; p < 3; ++p)
#pragma unroll
        for (int t2 = 0; t2 < 4; ++t2) acc[p][t2] = zero4();

#pragma unroll 2
    for (int kb = 0; kb < 8; ++kb) {
        int kc = kb * 32 + 8 * lg;
        f16x8 ah = *(const f16x8*)&xt[wn + li][kc];
#pragma unroll
        for (int p = 0; p < 3; ++p)
#pragma unroll
            for (int t2 = 0; t2 < 4; ++t2) {
                f16x8 bw = *(const f16x8*)&wf[(size_t)p * 32768
                               + (size_t)((ihb + t2) * 16 + li) * C_ + kc];
                acc[p][t2] = mfma16h(ah, bw, acc[p][t2]);
            }
    }
    f16* g3p = (f16*)(ws + G3_F);
    f16* thp = (f16*)(ws + TH_F);
    f16* php = (f16*)(ws + PH_F);
#pragma unroll
    for (int p = 0; p < 3; ++p) {
        const float* bias = (p == 0) ? bg : (p == 1) ? bth : bph;
#pragma unroll
        for (int t2 = 0; t2 < 4; ++t2) {
            int i = (ihb + t2) * 16 + li;
            float bs = bias[i];
#pragma unroll
            for (int r = 0; r < 4; ++r) {
                int n = n0 + wn + 4 * lg + r;
                float v = acc[p][t2][r] + bs;
                if (p == 0) {
                    int tq = (n >> 2) & 3;
                    size_t gi = ((size_t)b * (N_ / 32) + (n >> 5)) * 4096
                              + (size_t)(tq * 128 + (i ^ (tq << 1))) * 8
                              + ((n >> 4) & 1) * 4 + (n & 3);
                    g3p[gi] = (f16)v;
                } else if (p == 1)
                    thp[((size_t)b * N_ + n) * I_ + i] = (f16)(v * LOG2E);
                else
                    php[((size_t)b * N_ + n) * I_ + i] = (f16)v;
            }
        }
    }
}

// ---------------- kernel 3: flash attention, 32 q/wave, KVB=32 ---------------
// grid (32 qtiles, B, splits), 256 thr = 4 waves. Loop unrolled x2 with literal
// LDS buffer offsets; LDS read offsets hoisted to loop-invariant registers.
// launch_bounds (256,3): VGPR demand ~130; forcing 4 waves/EU (round 10)
// capped VGPRs at 64 -> scratch spills -> FETCH 250MB, 2x slowdown.
__global__ __launch_bounds__(256, 3) void k_attn(ushort_t* ws, float* lse, int splits) {
    __shared__ __align__(16) ushort_t smem[16384];  // 32KB: phi@0/4096, g@8192/12288
    int b = blockIdx.y, sp = blockIdx.z;
    int w = threadIdx.x >> 6, l = threadIdx.x & 63;
    int li = l & 15, lg = l >> 4;
    int q0 = blockIdx.x * 128 + w * 16;             // subtile A; subtile B at +64
    const f16* th = (const f16*)(ws + TH_F);
    const f16* ph = (const f16*)(ws + PH_F);
    const f16* g3 = (const f16*)(ws + G3_F);
    f16* yp = (f16*)(ws + YP_F) + (size_t)sp * 2097152ull;
    const f16* smf = (const f16*)smem;

    f16x8 qA[4], qB[4];
#pragma unroll
    for (int kb = 0; kb < 4; ++kb) {
        qA[kb] = *(const f16x8*)&th[((size_t)b * N_ + q0 + li) * I_ + kb * 32 + 8 * lg];
        qB[kb] = *(const f16x8*)&th[((size_t)b * N_ + q0 + 64 + li) * I_ + kb * 32 + 8 * lg];
    }

    // loop-invariant LDS read offsets (f16 units)
    int phOff[8];
#pragma unroll
    for (int kb = 0; kb < 4; ++kb) {
        int cc = ((kb * 4 + lg) ^ (li & 7)) * 8;
        phOff[kb * 2 + 0] = li * 128 + cc;
        phOff[kb * 2 + 1] = (16 + li) * 128 + cc;
    }
    // g: (dt*16+li)^(lg<<1) == dt*16 + (li^(lg<<1))  ->  base + dt*128
    int gBase = 8192 + (lg * 128 + (li ^ (lg << 1))) * 8;

    f32x4 yA[8], yB[8];
#pragma unroll
    for (int dt = 0; dt < 8; ++dt) { yA[dt] = zero4(); yB[dt] = zero4(); }
    float mA = -1e30f, lA = 0.f, mB = -1e30f, lB = 0.f;

    int beg = (sp * TOT_IT) / splits;
    int end = ((sp + 1) * TOT_IT) / splits;
    int nit = end - beg;
    int srow = l >> 4;
    const f16* srcP0 = ph + ((size_t)b * N_ + w * 8 + srow) * I_
                          + ((l & 15) ^ srow) * 8 + (size_t)beg * KVB * I_;
    const f16* srcP1 = ph + ((size_t)b * N_ + w * 8 + 4 + srow) * I_
                          + (((l & 15) ^ srow) ^ 4) * 8 + (size_t)beg * KVB * I_;
    const f16* srcG  = g3 + (size_t)b * (N_ / 32) * 4096 + w * 1024 + l * 8
                          + (size_t)beg * KVB * 128;

    // prologue: stage tile 0 into buffer 0
    gload_lds16(srcP0, smem + w * 1024);
    gload_lds16(srcP1, smem + w * 1024 + 512);
    gload_lds16(srcG,       smem + 8192 + w * 1024);
    gload_lds16(srcG + 512, smem + 8192 + w * 1024 + 512);
    srcP0 += 4096; srcP1 += 4096; srcG += 4096;
    __syncthreads();

#define ATTN_STEP(BUF, HASNEXT)                                                   \
    do {                                                                          \
        if (HASNEXT) {                                                            \
            gload_lds16(srcP0, smem + ((BUF) ^ 4096) + w * 1024);                 \
            gload_lds16(srcP1, smem + ((BUF) ^ 4096) + w * 1024 + 512);           \
            gload_lds16(srcG,       smem + 8192 + ((BUF) ^ 4096) + w * 1024);     \
            gload_lds16(srcG + 512, smem + 8192 + ((BUF) ^ 4096) + w * 1024 + 512);\
            srcP0 += 4096; srcP1 += 4096; srcG += 4096;                           \
        }                                                                         \
        f32x4 fA0 = zero4(), fA1 = zero4(), fB0 = zero4(), fB1 = zero4();         \
        __builtin_amdgcn_s_setprio(1);                                            \
        _Pragma("unroll")                                                         \
        for (int kb = 0; kb < 4; ++kb) {                                          \
            f16x8 a0 = *(const f16x8*)&smf[phOff[kb * 2 + 0] + (BUF)];            \
            f16x8 a1 = *(const f16x8*)&smf[phOff[kb * 2 + 1] + (BUF)];            \
            fA0 = mfma16h(a0, qA[kb], fA0);                                       \
            fB0 = mfma16h(a0, qB[kb], fB0);                                       \
            fA1 = mfma16h(a1, qA[kb], fA1);                                       \
            fB1 = mfma16h(a1, qB[kb], fB1);                                       \
        }                                                                         \
        __builtin_amdgcn_s_setprio(0);                                            \
        float tmA = fmaxf(fmaxf(fmaxf(fA0[0], fA0[1]), fmaxf(fA0[2], fA0[3])),    \
                          fmaxf(fmaxf(fA1[0], fA1[1]), fmaxf(fA1[2], fA1[3])));   \
        tmA = fmaxf(tmA, __shfl_xor(tmA, 16));                                    \
        tmA = fmaxf(tmA, __shfl_xor(tmA, 32));                                    \
        if (__ballot(tmA > mA + 11.0f)) {                                         \
            float mn = fmaxf(mA, tmA);                                            \
            float sc = exp2_hw(mA - mn);                                          \
            lA *= sc; mA = mn;                                                    \
            float s0 = __shfl(sc, 4 * lg + 0);                                    \
            float s1 = __shfl(sc, 4 * lg + 1);                                    \
            float s2 = __shfl(sc, 4 * lg + 2);                                    \
            float s3 = __shfl(sc, 4 * lg + 3);                                    \
            _Pragma("unroll")                                                     \
            for (int dt = 0; dt < 8; ++dt) {                                      \
                yA[dt][0] *= s0; yA[dt][1] *= s1;                                 \
                yA[dt][2] *= s2; yA[dt][3] *= s3;                                 \
            }                                                                     \
        }                                                                         \
        _Pragma("unroll")                                                         \
        for (int r = 0; r < 4; ++r) {                                             \
            fA0[r] = exp2_hw(fA0[r] - mA);                                        \
            fA1[r] = exp2_hw(fA1[r] - mA);                                        \
        }                                                                         \
        lA += ((fA0[0] + fA0[1]) + (fA0[2] + fA0[3]))                             \
            + ((fA1[0] + fA1[1]) + (fA1[2] + fA1[3]));                            \
        union PU { f16x2 h2[4]; f16x8 v; };                                       \
        PU pA, pB;                                                                \
        pA.h2[0] = pkrtz(fA0[0], fA0[1]); pA.h2[1] = pkrtz(fA0[2], fA0[3]);       \
        pA.h2[2] = pkrtz(fA1[0], fA1[1]); pA.h2[3] = pkrtz(fA1[2], fA1[3]);       \
        float tmB = fmaxf(fmaxf(fmaxf(fB0[0], fB0[1]), fmaxf(fB0[2], fB0[3])),    \
                          fmaxf(fmaxf(fB1[0], fB1[1]), fmaxf(fB1[2], fB1[3])));   \
        tmB = fmaxf(tmB, __shfl_xor(tmB, 16));                                    \
        tmB = fmaxf(tmB, __shfl_xor(tmB, 32));                                    \
        if (__ballot(tmB > mB + 11.0f)) {                                         \
            float mn = fmaxf(mB, tmB);                                            \
            float sc = exp2_hw(mB - mn);                                          \
            lB *= sc; mB = mn;                                                    \
            float s0 = __shfl(sc, 4 * lg + 0);                                    \
            float s1 = __shfl(sc, 4 * lg + 1);                                    \
            float s2 = __shfl(sc, 4 * lg + 2);                                    \
            float s3 = __shfl(sc, 4 * lg + 3);                                    \
            _Pragma("unroll")                                                     \
            for (int dt = 0; dt < 8; ++dt) {                                      \
                yB[dt][0] *= s0; yB[dt][1] *= s1;                                 \
                yB[dt][2] *= s2; yB[dt][3] *= s3;                                 \
            }                                                                     \
        }                                                                         \
        _Pragma("unroll")                                                         \
        for (int r = 0; r < 4; ++r) {                                             \
            fB0[r] = exp2_hw(fB0[r] - mB);                                        \
            fB1[r] = exp2_hw(fB1[r] - mB);                                        \
        }                                                                         \
        lB += ((fB0[0] + fB0[1]) + (fB0[2] + fB0[3]))                             \
            + ((fB1[0] + fB1[1]) + (fB1[2] + fB1[3]));                            \
        pB.h2[0] = pkrtz(fB0[0], fB0[1]); pB.h2[1] = pkrtz(fB0[2], fB0[3]);       \
        pB.h2[2] = pkrtz(fB1[0], fB1[1]); pB.h2[3] = pkrtz(fB1[2], fB1[3]);       \
        __builtin_amdgcn_s_setprio(1);                                            \
        _Pragma("unroll")                                                         \
        for (int dt = 0; dt < 8; ++dt) {                                          \
            f16x8 gv = *(const f16x8*)&smf[gBase + dt * 128 + (BUF)];             \
            yA[dt] = mfma16h(pA.v, gv, yA[dt]);                                   \
            yB[dt] = mfma16h(pB.v, gv, yB[dt]);                                   \
        }                                                                         \
        __builtin_amdgcn_s_setprio(0);                                            \
        __syncthreads();                                                          \
    } while (0)

    int it = 0;
    while (it + 2 <= nit) {
        ATTN_STEP(0, (it + 1 < nit));
        ATTN_STEP(4096, (it + 2 < nit));
        it += 2;
    }
    if (it < nit) ATTN_STEP(0, false);
#undef ATTN_STEP

    // epilogue: cross-lane sum (deferred), normalized partials + base-2 lse
    lA += __shfl_xor(lA, 16); lA += __shfl_xor(lA, 32);
    lB += __shfl_xor(lB, 16); lB += __shfl_xor(lB, 32);
    {
        float inv = 1.0f / lA;
        float i0 = __shfl(inv, 4 * lg + 0);
        float i1 = __shfl(inv, 4 * lg + 1);
        float i2 = __shfl(inv, 4 * lg + 2);
        float i3 = __shfl(inv, 4 * lg + 3);
#pragma unroll
        for (int dt = 0; dt < 8; ++dt) {
            size_t base = ((size_t)b * N_ + q0 + 4 * lg) * I_ + dt * 16 + li;
            yp[base]          = (f16)(yA[dt][0] * i0);
            yp[base + I_]     = (f16)(yA[dt][1] * i1);
            yp[base + 2 * I_] = (f16)(yA[dt][2] * i2);
            yp[base + 3 * I_] = (f16)(yA[dt][3] * i3);
        }
    }
    {
        float inv = 1.0f / lB;
        float i0 = __shfl(inv, 4 * lg + 0);
        float i1 = __shfl(inv, 4 * lg + 1);
        float i2 = __shfl(inv, 4 * lg + 2);
        float i3 = __shfl(inv, 4 * lg + 3);
#pragma unroll
        for (int dt = 0; dt < 8; ++dt) {
            size_t base = ((size_t)b * N_ + q0 + 64 + 4 * lg) * I_ + dt * 16 + li;
            yp[base]          = (f16)(yB[dt][0] * i0);
            yp[base + I_]     = (f16)(yB[dt][1] * i1);
            yp[base + 2 * I_] = (f16)(yB[dt][2] * i2);
            yp[base + 3 * I_] = (f16)(yB[dt][3] * i3);
        }
    }
    if (l < 16) {
        lse[((size_t)sp * B_ + b) * N_ + q0 + l]      = mA + log2_hw(lA);
        lse[((size_t)sp * B_ + b) * N_ + q0 + 64 + l] = mB + log2_hw(lB);
    }
}

// ------- kernel 4: fused split-merge + output projection + residual ----------
__global__ __launch_bounds__(512) void k_out(const float* x, const float* bW,
        const ushort_t* ws, const float* lse, float* out, int splits) {
    __shared__ __align__(16) f16 ylds[64 * 136];
    int b = blockIdx.y, n0 = blockIdx.x * 64;
    int tid = threadIdx.x;
    {
        int nn = tid >> 3, ig = tid & 7;
        size_t lrow = (size_t)b * N_ + n0 + nn;
        float mx = -1e30f;
        for (int s = 0; s < splits; ++s)
            mx = fmaxf(mx, lse[(size_t)s * (B_ * N_) + lrow]);
        float sum = 0.f;
        for (int s = 0; s < splits; ++s)
            sum += exp2_hw(lse[(size_t)s * (B_ * N_) + lrow] - mx);
        float inv = 1.0f / sum;
        float acc[16];
#pragma unroll
        for (int j = 0; j < 16; ++j) acc[j] = 0.f;
        for (int s = 0; s < splits; ++s) {
            float wg = exp2_hw(lse[(size_t)s * (B_ * N_) + lrow] - mx) * inv;
            const f16* p = (const f16*)(ws + YP_F) + (size_t)s * 2097152ull
                         + lrow * I_ + ig * 16;
            f16x8 v0 = *(const f16x8*)p;
            f16x8 v1 = *(const f16x8*)(p + 8);
#pragma unroll
            for (int j = 0; j < 8; ++j) {
                acc[j]     += wg * (float)v0[j];
                acc[8 + j] += wg * (float)v1[j];
            }
        }
        f16 o[16];
#pragma unroll
        for (int j = 0; j < 16; ++j) o[j] = (f16)acc[j];
        *(uint4*)&ylds[nn * 136 + ig * 16]     = *(uint4*)&o[0];
        *(uint4*)&ylds[nn * 136 + ig * 16 + 8] = *(uint4*)&o[8];
    }
    __syncthreads();

    int w = tid >> 6, l = tid & 63;
    int li = l & 15, lg = l >> 4;
    int cw = (w >> 1) * 64, nh = (w & 1) * 32;
    const f16* wfp = (const f16*)(ws + W_F) + 98304;   // w_W [256][128] f16

    f32x4 acc2[4][2];
#pragma unroll
    for (int mm = 0; mm < 4; ++mm)
#pragma unroll
        for (int n = 0; n < 2; ++n) acc2[mm][n] = zero4();

#pragma unroll 2
    for (int kb = 0; kb < 4; ++kb) {
        int kc = kb * 32 + 8 * lg;
        f16x8 a[4], byv[2];
#pragma unroll
        for (int mm = 0; mm < 4; ++mm)
            a[mm] = *(const f16x8*)&wfp[(size_t)(cw + mm * 16 + li) * I_ + kc];
#pragma unroll
        for (int n = 0; n < 2; ++n)
            byv[n] = *(const f16x8*)&ylds[(nh + n * 16 + li) * 136 + kc];
#pragma unroll
        for (int mm = 0; mm < 4; ++mm)
#pragma unroll
            for (int n = 0; n < 2; ++n)
                acc2[mm][n] = mfma16h(a[mm], byv[n], acc2[mm][n]);
    }
#pragma unroll
    for (int mm = 0; mm < 4; ++mm)
#pragma unroll
        for (int n = 0; n < 2; ++n)
#pragma unroll
            for (int r = 0; r < 4; ++r) {
                int c = cw + mm * 16 + lg * 4 + r;
                int nn = n0 + nh + n * 16 + li;
                size_t xi = ((size_t)b * C_ + c) * N_ + nn;
                out[xi] = acc2[mm][n][r] + bW[c] + x[xi];
            }
}

extern "C" void kernel_launch(void* const* d_in, const int* in_sizes, int n_in,
                              void* d_out, int out_size, void* d_ws, size_t ws_size,
                              hipStream_t stream) {
    const float* x  = (const float*)d_in[0];
    const float* wg = (const float*)d_in[1];
    const float* bg = (const float*)d_in[2];
    const float* wt = (const float*)d_in[3];
    const float* bt = (const float*)d_in[4];
    const float* wp = (const float*)d_in[5];
    const float* bp = (const float*)d_in[6];
    const float* wW = (const float*)d_in[7];
    const float* bW = (const float*)d_in[8];
    ushort_t* ws = (ushort_t*)d_ws;
    float* out = (float*)d_out;

    // footprint(S) = 2*(YP_F + S*2097152) + S*65536 bytes
    int splits = (ws_size >= 46923776ull) ? 8
               : (ws_size >= 42663936ull) ? 7
               : (ws_size >= 38404096ull) ? 6 : 4;
    size_t lse_off = 2ull * (YP_F + (size_t)splits * 2097152ull);
    float* lse = (float*)((char*)d_ws + lse_off);

    k_convert_w<<<32, 256, 0, stream>>>(wg, wt, wp, wW, ws);
    k_projx<<<dim3(64, 4), 512, 0, stream>>>(x, bg, bt, bp, ws);
    k_attn<<<dim3(32, 4, splits), 256, 0, stream>>>(ws, lse, splits);
    k_out<<<dim3(64, 4), 512, 0, stream>>>(x, bW, ws, lse, out, splits);
}